// Round 1
// baseline (1903.604 us; speedup 1.0000x reference)
//
#include <hip/hip_runtime.h>

#define EMB 64
constexpr int N_LAYERS = 3;
constexpr int OUT_D = EMB * (N_LAYERS + 1);  // 256

__device__ __forceinline__ float readlane_f(float v, int l) {
  return __int_as_float(__builtin_amdgcn_readlane(__float_as_int(v), l));
}

// ego[r][d] = masked embedding; also writes block 0 of all_emb [N][256]
__global__ void init_ego_kernel(const float* __restrict__ ue, const float* __restrict__ ie,
                                const int* __restrict__ usz, const int* __restrict__ isz,
                                float* __restrict__ ego, float* __restrict__ all_emb,
                                int n_users, int n_total) {
  int idx = blockIdx.x * blockDim.x + threadIdx.x;
  if (idx >= n_total * EMB) return;
  int r = idx >> 6, d = idx & 63;
  float v; int sz;
  if (r < n_users) {
    v = ue[idx];
    sz = usz[r];
  } else {
    int ri = r - n_users;
    v = ie[ri * EMB + d];
    sz = isz[ri];
  }
  v = (d < sz) ? v : 0.0f;
  ego[idx] = v;
  all_emb[(size_t)r * OUT_D + d] = v;
}

// side[row] += val * ego[col]  (COO, unsorted rows -> atomics)
// one wave per edge, lane = dim; 4 edges per wave iteration
__global__ __launch_bounds__(256) void spmm_atomic_kernel(
    const float* __restrict__ vals, const int* __restrict__ rows,
    const int* __restrict__ cols, const float* __restrict__ ego,
    float* __restrict__ side, int nnz) {
  int lane = threadIdx.x & 63;
  long wid = (long)blockIdx.x * (blockDim.x >> 6) + (threadIdx.x >> 6);
  long e0 = wid * 4;
#pragma unroll
  for (int i = 0; i < 4; ++i) {
    long e = e0 + i;
    if (e < nnz) {
      float v = vals[e];
      int r = rows[e];
      int c = cols[e];
      float x = ego[(long)c * EMB + lane];
      atomicAdd(&side[(long)r * EMB + lane], v * x);
    }
  }
}

// per row: sum_emb = side@Wgc + bgc ; bi = (ego*side)@Wbi + bbi ;
// ego_new = leaky_relu(sum+bi, 0.2) (stored UNNORMALIZED back into ego);
// all_emb[:, col_off:col_off+64] = ego_new / max(||ego_new||, 1e-12)
// wave per row; lane d holds W column d of both matrices in VGPRs.
__global__ __launch_bounds__(256) void layer_fused_kernel(
    const float* __restrict__ side, float* ego,
    const float* __restrict__ Wgc, const float* __restrict__ bgc,
    const float* __restrict__ Wbi, const float* __restrict__ bbi,
    float* __restrict__ all_emb, int nrows, int col_off) {
  int lane = threadIdx.x & 63;
  float wgc[EMB], wbi[EMB];
#pragma unroll
  for (int kk = 0; kk < EMB; ++kk) {
    wgc[kk] = Wgc[kk * EMB + lane];
    wbi[kk] = Wbi[kk * EMB + lane];
  }
  float bg = bgc[lane], bb = bbi[lane];
  int wid = blockIdx.x * (blockDim.x >> 6) + (threadIdx.x >> 6);
  int nw = gridDim.x * (blockDim.x >> 6);
  for (int r = wid; r < nrows; r += nw) {
    float s = side[(long)r * EMB + lane];
    float e = ego[(long)r * EMB + lane];
    float es = e * s;
    float accg = bg, accb = bb;
#pragma unroll
    for (int kk = 0; kk < EMB; ++kk) {
      accg = fmaf(readlane_f(s, kk), wgc[kk], accg);
      accb = fmaf(readlane_f(es, kk), wbi[kk], accb);
    }
    float o = accg + accb;
    o = (o >= 0.0f) ? o : 0.2f * o;
    ego[(long)r * EMB + lane] = o;
    float sq = o * o;
#pragma unroll
    for (int off = 32; off; off >>= 1) sq += __shfl_xor(sq, off, 64);
    float norm = fmaxf(sqrtf(sq), 1e-12f);
    all_emb[(size_t)r * OUT_D + col_off + lane] = o / norm;
  }
}

// out[0:B] = all_emb[users], out[B:2B] = all_emb[NU+pos], out[2B:3B] = all_emb[NU+neg]
__global__ void gather_out_kernel(const float* __restrict__ all_emb,
                                  const int* __restrict__ users,
                                  const int* __restrict__ pos,
                                  const int* __restrict__ neg,
                                  float* __restrict__ out, int n_users, int B) {
  int row = blockIdx.x;  // [0, B)
  int sec = blockIdx.y;  // 0,1,2
  int t = threadIdx.x;   // 256 = OUT_D
  int src;
  if (sec == 0) src = users[row];
  else if (sec == 1) src = n_users + pos[row];
  else src = n_users + neg[row];
  out[((size_t)sec * B + row) * OUT_D + t] = all_emb[(size_t)src * OUT_D + t];
}

extern "C" void kernel_launch(void* const* d_in, const int* in_sizes, int n_in,
                              void* d_out, int out_size, void* d_ws, size_t ws_size,
                              hipStream_t stream) {
  const float* user_emb = (const float*)d_in[0];
  const float* item_emb = (const float*)d_in[1];
  const float* W_gc = (const float*)d_in[2];
  const float* b_gc = (const float*)d_in[3];
  const float* W_bi = (const float*)d_in[4];
  const float* b_bi = (const float*)d_in[5];
  const float* adj_vals = (const float*)d_in[6];
  const int* adj_rows = (const int*)d_in[7];
  const int* adj_cols = (const int*)d_in[8];
  const int* user_sizes = (const int*)d_in[9];
  const int* item_sizes = (const int*)d_in[10];
  const int* users = (const int*)d_in[11];
  const int* pos_items = (const int*)d_in[12];
  const int* neg_items = (const int*)d_in[13];

  const int n_users = in_sizes[9];
  const int n_items = in_sizes[10];
  const int N = n_users + n_items;
  const int nnz = in_sizes[6];
  const int B = in_sizes[11];

  // workspace layout (floats): all_emb [N*256] | ego [N*64] | side [N*64]
  float* all_emb = (float*)d_ws;
  float* ego = all_emb + (size_t)N * OUT_D;
  float* side = ego + (size_t)N * EMB;

  {
    int total = N * EMB;
    int blocks = (total + 255) / 256;
    hipLaunchKernelGGL(init_ego_kernel, dim3(blocks), dim3(256), 0, stream,
                       user_emb, item_emb, user_sizes, item_sizes, ego, all_emb,
                       n_users, N);
  }

  for (int k = 0; k < N_LAYERS; ++k) {
    hipMemsetAsync(side, 0, (size_t)N * EMB * sizeof(float), stream);
    int blocks = (nnz + 15) / 16;  // 4 waves/block * 4 edges/wave
    hipLaunchKernelGGL(spmm_atomic_kernel, dim3(blocks), dim3(256), 0, stream,
                       adj_vals, adj_rows, adj_cols, ego, side, nnz);
    hipLaunchKernelGGL(layer_fused_kernel, dim3(2048), dim3(256), 0, stream,
                       side, ego, W_gc + k * EMB * EMB, b_gc + k * EMB,
                       W_bi + k * EMB * EMB, b_bi + k * EMB, all_emb, N,
                       (k + 1) * EMB);
  }

  hipLaunchKernelGGL(gather_out_kernel, dim3(B, 3), dim3(256), 0, stream,
                     all_emb, users, pos_items, neg_items, (float*)d_out,
                     n_users, B);
}

// Round 2
// 851.165 us; speedup vs baseline: 2.2365x; 2.2365x over previous
//
#include <hip/hip_runtime.h>

#define EMB 64
constexpr int N_LAYERS = 3;
constexpr int OUT_D = EMB * (N_LAYERS + 1);  // 256
constexpr int SCAN_B = 256;

__device__ __forceinline__ float readlane_f(float v, int l) {
  return __int_as_float(__builtin_amdgcn_readlane(__float_as_int(v), l));
}
__device__ __forceinline__ int readlane_i(int v, int l) {
  return __builtin_amdgcn_readlane(v, l);
}

// ego[r][d] = masked embedding; also writes block 0 of all_emb [N][256]
__global__ void init_ego_kernel(const float* __restrict__ ue, const float* __restrict__ ie,
                                const int* __restrict__ usz, const int* __restrict__ isz,
                                float* __restrict__ ego, float* __restrict__ all_emb,
                                int n_users, int n_total) {
  int idx = blockIdx.x * blockDim.x + threadIdx.x;
  if (idx >= n_total * EMB) return;
  int r = idx >> 6, d = idx & 63;
  float v; int sz;
  if (r < n_users) {
    v = ue[idx];
    sz = usz[r];
  } else {
    int ri = r - n_users;
    v = ie[ri * EMB + d];
    sz = isz[ri];
  }
  v = (d < sz) ? v : 0.0f;
  ego[idx] = v;
  all_emb[(size_t)r * OUT_D + d] = v;
}

// ---------- CSR build: histogram -> exclusive scan -> scatter ----------

__global__ __launch_bounds__(256) void hist_kernel(const int* __restrict__ rows,
                                                   int* __restrict__ cnt, int nnz) {
  int i = blockIdx.x * blockDim.x + threadIdx.x;
  int stride = gridDim.x * blockDim.x;
  for (; i < nnz; i += stride) atomicAdd(&cnt[rows[i]], 1);
}

// scan over M = N+1 elements (cnt index N reads as 0). excl = per-block exclusive scan.
__global__ __launch_bounds__(SCAN_B) void scan1_kernel(const int* __restrict__ cnt,
                                                       int* __restrict__ excl,
                                                       int* __restrict__ bsum,
                                                       int n /*=N*/, int M /*=N+1*/) {
  __shared__ int sm[SCAN_B];
  int t = threadIdx.x;
  int idx = blockIdx.x * SCAN_B + t;
  int x = (idx < n) ? cnt[idx] : 0;
  sm[t] = x;
  __syncthreads();
#pragma unroll
  for (int off = 1; off < SCAN_B; off <<= 1) {
    int y = (t >= off) ? sm[t - off] : 0;
    __syncthreads();
    sm[t] += y;
    __syncthreads();
  }
  if (idx < M) excl[idx] = sm[t] - x;
  if (t == SCAN_B - 1) bsum[blockIdx.x] = sm[t];
}

__global__ __launch_bounds__(512) void scan2_kernel(int* __restrict__ bsum, int nb) {
  __shared__ int sm[512];
  int t = threadIdx.x;
  int x = (t < nb) ? bsum[t] : 0;
  sm[t] = x;
  __syncthreads();
#pragma unroll
  for (int off = 1; off < 512; off <<= 1) {
    int y = (t >= off) ? sm[t - off] : 0;
    __syncthreads();
    sm[t] += y;
    __syncthreads();
  }
  if (t < nb) bsum[t] = sm[t] - x;  // exclusive
}

__global__ __launch_bounds__(SCAN_B) void scan3_kernel(int* __restrict__ excl,
                                                       const int* __restrict__ bsum,
                                                       int* __restrict__ cursor, int M) {
  int idx = blockIdx.x * SCAN_B + threadIdx.x;
  if (idx < M) {
    int v = excl[idx] + bsum[blockIdx.x];
    excl[idx] = v;
    cursor[idx] = v;
  }
}

__global__ __launch_bounds__(256) void scatter_kernel(
    const float* __restrict__ vals, const int* __restrict__ rows,
    const int* __restrict__ cols, int* __restrict__ cursor,
    float* __restrict__ sval, int* __restrict__ scol, int nnz) {
  int i = blockIdx.x * blockDim.x + threadIdx.x;
  int stride = gridDim.x * blockDim.x;
  for (; i < nnz; i += stride) {
    int r = rows[i];
    int p = atomicAdd(&cursor[r], 1);
    sval[p] = vals[i];
    scol[p] = cols[i];
  }
}

// ---------- atomic-free CSR SpMM: one wave per row, lane = dim ----------
__global__ __launch_bounds__(256) void spmm_csr_kernel(
    const int* __restrict__ rp, const float* __restrict__ sval,
    const int* __restrict__ scol, const float* __restrict__ ego,
    float* __restrict__ side, int nrows) {
  int lane = threadIdx.x & 63;
  int r = blockIdx.x * (blockDim.x >> 6) + (threadIdx.x >> 6);
  if (r >= nrows) return;
  int start = rp[r], end = rp[r + 1];
  float acc = 0.0f;
  for (int base = start; base < end; base += 64) {
    int m = end - base;
    if (m > 64) m = 64;
    int c_l = (base + lane < end) ? scol[base + lane] : 0;
    float v_l = (base + lane < end) ? sval[base + lane] : 0.0f;
    int kk = 0;
    for (; kk + 4 <= m; kk += 4) {
      int c0 = readlane_i(c_l, kk), c1 = readlane_i(c_l, kk + 1);
      int c2 = readlane_i(c_l, kk + 2), c3 = readlane_i(c_l, kk + 3);
      float v0 = readlane_f(v_l, kk), v1 = readlane_f(v_l, kk + 1);
      float v2 = readlane_f(v_l, kk + 2), v3 = readlane_f(v_l, kk + 3);
      float x0 = ego[c0 * EMB + lane];
      float x1 = ego[c1 * EMB + lane];
      float x2 = ego[c2 * EMB + lane];
      float x3 = ego[c3 * EMB + lane];
      acc = fmaf(v0, x0, acc);
      acc = fmaf(v1, x1, acc);
      acc = fmaf(v2, x2, acc);
      acc = fmaf(v3, x3, acc);
    }
    for (; kk < m; ++kk) {
      int c = readlane_i(c_l, kk);
      float v = readlane_f(v_l, kk);
      acc = fmaf(v, ego[c * EMB + lane], acc);
    }
  }
  side[(size_t)r * EMB + lane] = acc;
}

// per row: sum_emb = side@Wgc + bgc ; bi = (ego*side)@Wbi + bbi ;
// ego_new = leaky_relu(sum+bi, 0.2) (stored UNNORMALIZED back into ego);
// all_emb[:, col_off:col_off+64] = ego_new / max(||ego_new||, 1e-12)
__global__ __launch_bounds__(256) void layer_fused_kernel(
    const float* __restrict__ side, float* ego,
    const float* __restrict__ Wgc, const float* __restrict__ bgc,
    const float* __restrict__ Wbi, const float* __restrict__ bbi,
    float* __restrict__ all_emb, int nrows, int col_off) {
  int lane = threadIdx.x & 63;
  float wgc[EMB], wbi[EMB];
#pragma unroll
  for (int kk = 0; kk < EMB; ++kk) {
    wgc[kk] = Wgc[kk * EMB + lane];
    wbi[kk] = Wbi[kk * EMB + lane];
  }
  float bg = bgc[lane], bb = bbi[lane];
  int wid = blockIdx.x * (blockDim.x >> 6) + (threadIdx.x >> 6);
  int nw = gridDim.x * (blockDim.x >> 6);
  for (int r = wid; r < nrows; r += nw) {
    float s = side[(size_t)r * EMB + lane];
    float e = ego[(size_t)r * EMB + lane];
    float es = e * s;
    float accg = bg, accb = bb;
#pragma unroll
    for (int kk = 0; kk < EMB; ++kk) {
      accg = fmaf(readlane_f(s, kk), wgc[kk], accg);
      accb = fmaf(readlane_f(es, kk), wbi[kk], accb);
    }
    float o = accg + accb;
    o = (o >= 0.0f) ? o : 0.2f * o;
    ego[(size_t)r * EMB + lane] = o;
    float sq = o * o;
#pragma unroll
    for (int off = 32; off; off >>= 1) sq += __shfl_xor(sq, off, 64);
    float norm = fmaxf(sqrtf(sq), 1e-12f);
    all_emb[(size_t)r * OUT_D + col_off + lane] = o / norm;
  }
}

__global__ void gather_out_kernel(const float* __restrict__ all_emb,
                                  const int* __restrict__ users,
                                  const int* __restrict__ pos,
                                  const int* __restrict__ neg,
                                  float* __restrict__ out, int n_users, int B) {
  int row = blockIdx.x;
  int sec = blockIdx.y;
  int t = threadIdx.x;
  int src;
  if (sec == 0) src = users[row];
  else if (sec == 1) src = n_users + pos[row];
  else src = n_users + neg[row];
  out[((size_t)sec * B + row) * OUT_D + t] = all_emb[(size_t)src * OUT_D + t];
}

extern "C" void kernel_launch(void* const* d_in, const int* in_sizes, int n_in,
                              void* d_out, int out_size, void* d_ws, size_t ws_size,
                              hipStream_t stream) {
  const float* user_emb = (const float*)d_in[0];
  const float* item_emb = (const float*)d_in[1];
  const float* W_gc = (const float*)d_in[2];
  const float* b_gc = (const float*)d_in[3];
  const float* W_bi = (const float*)d_in[4];
  const float* b_bi = (const float*)d_in[5];
  const float* adj_vals = (const float*)d_in[6];
  const int* adj_rows = (const int*)d_in[7];
  const int* adj_cols = (const int*)d_in[8];
  const int* user_sizes = (const int*)d_in[9];
  const int* item_sizes = (const int*)d_in[10];
  const int* users = (const int*)d_in[11];
  const int* pos_items = (const int*)d_in[12];
  const int* neg_items = (const int*)d_in[13];

  const int n_users = in_sizes[9];
  const int n_items = in_sizes[10];
  const int N = n_users + n_items;
  const int nnz = in_sizes[6];
  const int B = in_sizes[11];
  const int M = N + 1;

  // workspace layout:
  // all_emb [N*256]f | ego [N*64]f | side [N*64]f | row_ptr [N+1]i | cursor [N+1]i |
  // bsum [512]i | sval [nnz]f | scol [nnz]i
  float* all_emb = (float*)d_ws;
  float* ego = all_emb + (size_t)N * OUT_D;
  float* side = ego + (size_t)N * EMB;
  int* row_ptr = (int*)(side + (size_t)N * EMB);
  int* cursor = row_ptr + M;
  int* bsum = cursor + M;
  float* sval = (float*)(bsum + 512);
  int* scol = (int*)(sval + nnz);

  // --- init ego + all_emb block 0 ---
  {
    int total = N * EMB;
    hipLaunchKernelGGL(init_ego_kernel, dim3((total + 255) / 256), dim3(256), 0,
                       stream, user_emb, item_emb, user_sizes, item_sizes, ego,
                       all_emb, n_users, N);
  }

  // --- build CSR (counting sort by row) ---
  hipMemsetAsync(cursor, 0, (size_t)M * sizeof(int), stream);  // counts
  hipLaunchKernelGGL(hist_kernel, dim3(2048), dim3(256), 0, stream, adj_rows,
                     cursor, nnz);
  int nb = (M + SCAN_B - 1) / SCAN_B;  // 391 for N=100000
  hipLaunchKernelGGL(scan1_kernel, dim3(nb), dim3(SCAN_B), 0, stream, cursor,
                     row_ptr, bsum, N, M);
  hipLaunchKernelGGL(scan2_kernel, dim3(1), dim3(512), 0, stream, bsum, nb);
  hipLaunchKernelGGL(scan3_kernel, dim3(nb), dim3(SCAN_B), 0, stream, row_ptr,
                     bsum, cursor, M);
  hipLaunchKernelGGL(scatter_kernel, dim3(2048), dim3(256), 0, stream, adj_vals,
                     adj_rows, adj_cols, cursor, sval, scol, nnz);

  // --- 3 propagation layers ---
  for (int k = 0; k < N_LAYERS; ++k) {
    hipLaunchKernelGGL(spmm_csr_kernel, dim3((N + 3) / 4), dim3(256), 0, stream,
                       row_ptr, sval, scol, ego, side, N);
    hipLaunchKernelGGL(layer_fused_kernel, dim3(2048), dim3(256), 0, stream,
                       side, ego, W_gc + k * EMB * EMB, b_gc + k * EMB,
                       W_bi + k * EMB * EMB, b_bi + k * EMB, all_emb, N,
                       (k + 1) * EMB);
  }

  hipLaunchKernelGGL(gather_out_kernel, dim3(B, 3), dim3(256), 0, stream,
                     all_emb, users, pos_items, neg_items, (float*)d_out,
                     n_users, B);
}

// Round 3
// 821.246 us; speedup vs baseline: 2.3179x; 1.0364x over previous
//
#include <hip/hip_runtime.h>

#define EMB 64
constexpr int N_LAYERS = 3;
constexpr int OUT_D = EMB * (N_LAYERS + 1);  // 256
constexpr int SCAN_B = 256;

__device__ __forceinline__ float readlane_f(float v, int l) {
  return __int_as_float(__builtin_amdgcn_readlane(__float_as_int(v), l));
}
__device__ __forceinline__ int readlane_i(int v, int l) {
  return __builtin_amdgcn_readlane(v, l);
}

// ego[r][d] = masked embedding; also writes block 0 of all_emb [N][256]
__global__ void init_ego_kernel(const float* __restrict__ ue, const float* __restrict__ ie,
                                const int* __restrict__ usz, const int* __restrict__ isz,
                                float* __restrict__ ego, float* __restrict__ all_emb,
                                int n_users, int n_total) {
  int idx = blockIdx.x * blockDim.x + threadIdx.x;
  if (idx >= n_total * EMB) return;
  int r = idx >> 6, d = idx & 63;
  float v; int sz;
  if (r < n_users) {
    v = ue[idx];
    sz = usz[r];
  } else {
    int ri = r - n_users;
    v = ie[ri * EMB + d];
    sz = isz[ri];
  }
  v = (d < sz) ? v : 0.0f;
  ego[idx] = v;
  all_emb[(size_t)r * OUT_D + d] = v;
}

// ---------- CSR build: histogram -> exclusive scan -> scatter ----------

__global__ __launch_bounds__(256) void hist_kernel(const int* __restrict__ rows,
                                                   int* __restrict__ cnt, int nnz) {
  int i = blockIdx.x * blockDim.x + threadIdx.x;
  int stride = gridDim.x * blockDim.x;
  for (; i < nnz; i += stride) atomicAdd(&cnt[rows[i]], 1);
}

__global__ __launch_bounds__(SCAN_B) void scan1_kernel(const int* __restrict__ cnt,
                                                       int* __restrict__ excl,
                                                       int* __restrict__ bsum,
                                                       int n /*=N*/, int M /*=N+1*/) {
  __shared__ int sm[SCAN_B];
  int t = threadIdx.x;
  int idx = blockIdx.x * SCAN_B + t;
  int x = (idx < n) ? cnt[idx] : 0;
  sm[t] = x;
  __syncthreads();
#pragma unroll
  for (int off = 1; off < SCAN_B; off <<= 1) {
    int y = (t >= off) ? sm[t - off] : 0;
    __syncthreads();
    sm[t] += y;
    __syncthreads();
  }
  if (idx < M) excl[idx] = sm[t] - x;
  if (t == SCAN_B - 1) bsum[blockIdx.x] = sm[t];
}

__global__ __launch_bounds__(512) void scan2_kernel(int* __restrict__ bsum, int nb) {
  __shared__ int sm[512];
  int t = threadIdx.x;
  int x = (t < nb) ? bsum[t] : 0;
  sm[t] = x;
  __syncthreads();
#pragma unroll
  for (int off = 1; off < 512; off <<= 1) {
    int y = (t >= off) ? sm[t - off] : 0;
    __syncthreads();
    sm[t] += y;
    __syncthreads();
  }
  if (t < nb) bsum[t] = sm[t] - x;  // exclusive
}

__global__ __launch_bounds__(SCAN_B) void scan3_kernel(int* __restrict__ excl,
                                                       const int* __restrict__ bsum,
                                                       int* __restrict__ cursor, int M) {
  int idx = blockIdx.x * SCAN_B + threadIdx.x;
  if (idx < M) {
    int v = excl[idx] + bsum[blockIdx.x];
    excl[idx] = v;
    cursor[idx] = v;
  }
}

// packed scatter: one 8B store {val, col} per edge
__global__ __launch_bounds__(256) void scatter_kernel(
    const float* __restrict__ vals, const int* __restrict__ rows,
    const int* __restrict__ cols, int* __restrict__ cursor,
    int2* __restrict__ edges, int nnz) {
  int i = blockIdx.x * blockDim.x + threadIdx.x;
  int stride = gridDim.x * blockDim.x;
  for (; i < nnz; i += stride) {
    int r = rows[i];
    int p = atomicAdd(&cursor[r], 1);
    edges[p] = make_int2(__float_as_int(vals[i]), cols[i]);
  }
}

// ---------- atomic-free CSR SpMM: one wave per row, lane = dim ----------
__global__ __launch_bounds__(256) void spmm_csr_kernel(
    const int* __restrict__ rp, const int2* __restrict__ edges,
    const float* __restrict__ ego, float* __restrict__ side, int nrows) {
  int lane = threadIdx.x & 63;
  int r = blockIdx.x * (blockDim.x >> 6) + (threadIdx.x >> 6);
  if (r >= nrows) return;
  int start = rp[r], end = rp[r + 1];
  float acc = 0.0f;
  for (int base = start; base < end; base += 64) {
    int m = end - base;
    if (m > 64) m = 64;
    int2 e = (base + lane < end) ? edges[base + lane] : make_int2(0, 0);
    float v_l = __int_as_float(e.x);
    int c_l = e.y;
    int kk = 0;
    for (; kk + 8 <= m; kk += 8) {
      int c[8];
      float v[8], x[8];
#pragma unroll
      for (int u = 0; u < 8; ++u) {
        c[u] = readlane_i(c_l, kk + u);
        v[u] = readlane_f(v_l, kk + u);
      }
#pragma unroll
      for (int u = 0; u < 8; ++u) x[u] = ego[(size_t)c[u] * EMB + lane];
#pragma unroll
      for (int u = 0; u < 8; ++u) acc = fmaf(v[u], x[u], acc);
    }
    for (; kk < m; ++kk) {
      int c = readlane_i(c_l, kk);
      float v = readlane_f(v_l, kk);
      acc = fmaf(v, ego[(size_t)c * EMB + lane], acc);
    }
  }
  side[(size_t)r * EMB + lane] = acc;
}

// per row: sum_emb = side@Wgc + bgc ; bi = (ego*side)@Wbi + bbi ;
// ego_new = leaky_relu(sum+bi, 0.2) (stored UNNORMALIZED back into ego);
// all_emb[:, col_off:col_off+64] = ego_new / max(||ego_new||, 1e-12)
__global__ __launch_bounds__(256) void layer_fused_kernel(
    const float* __restrict__ side, float* ego,
    const float* __restrict__ Wgc, const float* __restrict__ bgc,
    const float* __restrict__ Wbi, const float* __restrict__ bbi,
    float* __restrict__ all_emb, int nrows, int col_off) {
  int lane = threadIdx.x & 63;
  float wgc[EMB], wbi[EMB];
#pragma unroll
  for (int kk = 0; kk < EMB; ++kk) {
    wgc[kk] = Wgc[kk * EMB + lane];
    wbi[kk] = Wbi[kk * EMB + lane];
  }
  float bg = bgc[lane], bb = bbi[lane];
  int wid = blockIdx.x * (blockDim.x >> 6) + (threadIdx.x >> 6);
  int nw = gridDim.x * (blockDim.x >> 6);
  for (int r = wid; r < nrows; r += nw) {
    float s = side[(size_t)r * EMB + lane];
    float e = ego[(size_t)r * EMB + lane];
    float es = e * s;
    float accg = bg, accb = bb;
#pragma unroll
    for (int kk = 0; kk < EMB; ++kk) {
      accg = fmaf(readlane_f(s, kk), wgc[kk], accg);
      accb = fmaf(readlane_f(es, kk), wbi[kk], accb);
    }
    float o = accg + accb;
    o = (o >= 0.0f) ? o : 0.2f * o;
    ego[(size_t)r * EMB + lane] = o;
    float sq = o * o;
#pragma unroll
    for (int off = 32; off; off >>= 1) sq += __shfl_xor(sq, off, 64);
    float norm = fmaxf(sqrtf(sq), 1e-12f);
    all_emb[(size_t)r * OUT_D + col_off + lane] = o / norm;
  }
}

__global__ void gather_out_kernel(const float* __restrict__ all_emb,
                                  const int* __restrict__ users,
                                  const int* __restrict__ pos,
                                  const int* __restrict__ neg,
                                  float* __restrict__ out, int n_users, int B) {
  int row = blockIdx.x;
  int sec = blockIdx.y;
  int t = threadIdx.x;
  int src;
  if (sec == 0) src = users[row];
  else if (sec == 1) src = n_users + pos[row];
  else src = n_users + neg[row];
  out[((size_t)sec * B + row) * OUT_D + t] = all_emb[(size_t)src * OUT_D + t];
}

extern "C" void kernel_launch(void* const* d_in, const int* in_sizes, int n_in,
                              void* d_out, int out_size, void* d_ws, size_t ws_size,
                              hipStream_t stream) {
  const float* user_emb = (const float*)d_in[0];
  const float* item_emb = (const float*)d_in[1];
  const float* W_gc = (const float*)d_in[2];
  const float* b_gc = (const float*)d_in[3];
  const float* W_bi = (const float*)d_in[4];
  const float* b_bi = (const float*)d_in[5];
  const float* adj_vals = (const float*)d_in[6];
  const int* adj_rows = (const int*)d_in[7];
  const int* adj_cols = (const int*)d_in[8];
  const int* user_sizes = (const int*)d_in[9];
  const int* item_sizes = (const int*)d_in[10];
  const int* users = (const int*)d_in[11];
  const int* pos_items = (const int*)d_in[12];
  const int* neg_items = (const int*)d_in[13];

  const int n_users = in_sizes[9];
  const int n_items = in_sizes[10];
  const int N = n_users + n_items;
  const int nnz = in_sizes[6];
  const int B = in_sizes[11];
  const int M = N + 1;

  // workspace layout (ints/floats are 4B; edges 8B-aligned by construction):
  // all_emb [N*256]f | ego [N*64]f | side [N*64]f | row_ptr [M]i | cursor [M]i |
  // bsum [512]i | edges [nnz]int2
  float* all_emb = (float*)d_ws;
  float* ego = all_emb + (size_t)N * OUT_D;
  float* side = ego + (size_t)N * EMB;
  int* row_ptr = (int*)(side + (size_t)N * EMB);
  int* cursor = row_ptr + M;
  int* bsum = cursor + M;
  int2* edges = (int2*)(bsum + 512);

  {
    int total = N * EMB;
    hipLaunchKernelGGL(init_ego_kernel, dim3((total + 255) / 256), dim3(256), 0,
                       stream, user_emb, item_emb, user_sizes, item_sizes, ego,
                       all_emb, n_users, N);
  }

  // --- build CSR (counting sort by row) ---
  hipMemsetAsync(cursor, 0, (size_t)M * sizeof(int), stream);
  hipLaunchKernelGGL(hist_kernel, dim3(2048), dim3(256), 0, stream, adj_rows,
                     cursor, nnz);
  int nb = (M + SCAN_B - 1) / SCAN_B;
  hipLaunchKernelGGL(scan1_kernel, dim3(nb), dim3(SCAN_B), 0, stream, cursor,
                     row_ptr, bsum, N, M);
  hipLaunchKernelGGL(scan2_kernel, dim3(1), dim3(512), 0, stream, bsum, nb);
  hipLaunchKernelGGL(scan3_kernel, dim3(nb), dim3(SCAN_B), 0, stream, row_ptr,
                     bsum, cursor, M);
  hipLaunchKernelGGL(scatter_kernel, dim3(2048), dim3(256), 0, stream, adj_vals,
                     adj_rows, adj_cols, cursor, edges, nnz);

  // --- 3 propagation layers ---
  for (int k = 0; k < N_LAYERS; ++k) {
    hipLaunchKernelGGL(spmm_csr_kernel, dim3((N + 3) / 4), dim3(256), 0, stream,
                       row_ptr, edges, ego, side, N);
    hipLaunchKernelGGL(layer_fused_kernel, dim3(2048), dim3(256), 0, stream,
                       side, ego, W_gc + k * EMB * EMB, b_gc + k * EMB,
                       W_bi + k * EMB * EMB, b_bi + k * EMB, all_emb, N,
                       (k + 1) * EMB);
  }

  hipLaunchKernelGGL(gather_out_kernel, dim3(B, 3), dim3(256), 0, stream,
                     all_emb, users, pos_items, neg_items, (float*)d_out,
                     n_users, B);
}